// Round 1
// baseline (753.167 us; speedup 1.0000x reference)
//
#include <hip/hip_runtime.h>
#include <hip/hip_cooperative_groups.h>
#include <math.h>

namespace cg = cooperative_groups;

typedef __attribute__((ext_vector_type(8))) short bf16x8;
typedef __attribute__((ext_vector_type(4))) float f32x4;

__device__ __forceinline__ unsigned short f2bf(float f) {
    unsigned u = __builtin_bit_cast(unsigned, f);
    u += 0x7FFF + ((u >> 16) & 1);          // RNE
    return (unsigned short)(u >> 16);
}
__device__ __forceinline__ float bf2f(unsigned short h) {
    unsigned u = ((unsigned)h) << 16;
    return __builtin_bit_cast(float, u);
}

// Packed-weight offsets inside Wb (bf16 elements)
#define O_W3 0
#define O_W4 6144
#define O_W5 18432
#define O_W6 30720
#define O_W7 55296
#define O_W8 153600
#define O_W9 546816
#define O_W10 1333248
#define O_W11 2119680

struct MegaParams {
    const float* x;
    const float* W1; const float* B1; const int* S1;
    const float* W2; const float* B2; const int* S2;
    const float* Wsrc[9];          // W3..W11 fp32
    const float* Bl[9];            // B3..B11
    const int*   Sl[9];            // S3..S11
    const float* fcW; const float* fcb;
    unsigned short* Wb;            // packed bf16 weights
    unsigned short* bufA;
    unsigned short* bufB;
    float* out;
};

// ============================================================================
// MFMA helpers (verified R9/R11/R12 of previous session)
// ============================================================================
template<int CIN>
__device__ __forceinline__ void mfma_tile(
    const unsigned short* a0, const unsigned short* a1,
    const unsigned short* b0p, const unsigned short* b1p,
    f32x4& acc0, f32x4& acc1)
{
#pragma unroll
    for (int k = 0; k < CIN; k += 32) {
        bf16x8 A0 = __builtin_bit_cast(bf16x8, *(const float4*)(const void*)(a0 + k));
        bf16x8 A1 = __builtin_bit_cast(bf16x8, *(const float4*)(const void*)(a1 + k));
        bf16x8 B0 = __builtin_bit_cast(bf16x8, *(const float4*)(const void*)(b0p + k));
        bf16x8 B1 = __builtin_bit_cast(bf16x8, *(const float4*)(const void*)(b1p + k));
        acc0 = __builtin_amdgcn_mfma_f32_16x16x32_bf16(A0, B0, acc0, 0, 0, 0);
        acc1 = __builtin_amdgcn_mfma_f32_16x16x32_bf16(A1, B1, acc1, 0, 0, 0);
    }
}

__device__ __forceinline__ void epilogue_store(
    unsigned short* dst, const f32x4& acc0, const f32x4& acc1,
    const float* bias, int fbase, int s0, int s1)
{
    unsigned short o[4];
#pragma unroll
    for (int r = 0; r < 4; ++r) {
        float v = fmaxf(fmaxf(acc0[r] + bias[(fbase + r) * 3 + s0],
                              acc1[r] + bias[(fbase + r) * 3 + s1]), 0.f);
        o[r] = f2bf(v);
    }
    *(ushort4*)dst = make_ushort4(o[0], o[1], o[2], o[3]);
}

// ============================================================================
// Phase 0: [blocks 0..127] L1+L2 fused via LDS | [blocks 128..255] pack W3..W11
// writes X3 = bufA [512][128][32], Wb
// ============================================================================
__device__ __forceinline__ void phase0(const MegaParams& P)
{
    const int tid = threadIdx.x;

    if (blockIdx.x >= 128) {
        int gt = (blockIdx.x - 128) * 256 + tid;
        const int we[9] = {6144, 12288, 12288, 24576, 98304, 393216, 786432, 786432, 1572864};
        int off = 0;
#pragma unroll
        for (int li = 0; li < 9; ++li) {
            const float4* src = (const float4*)P.Wsrc[li];
            ushort4* dst = (ushort4*)(P.Wb + off);
            int n4 = we[li] >> 2;
            for (int i = gt; i < n4; i += 32768) {
                float4 w = src[i];
                dst[i] = make_ushort4(f2bf(w.x), f2bf(w.y), f2bf(w.z), f2bf(w.w));
            }
            off += we[li];
        }
        return;
    }

    __shared__ float wl1[72], bl1[24], wl2[768], bl2[96];
    __shared__ unsigned short bufL1[16 * 64 * 8];

    if (tid < 72) wl1[tid] = P.W1[tid];
    if (tid >= 128 && tid < 152) bl1[tid - 128] = P.B1[tid - 128];
    for (int i = tid; i < 768; i += 256) wl2[i] = P.W2[i];
    if (tid < 96) bl2[tid] = P.B2[tid];
    __syncthreads();

    const int npT = blockIdx.x >> 1;          // 0..63
    const int b0  = (blockIdx.x & 1) * 64;

    for (int i = tid; i < 1024; i += 256) {
        int pos_l = i >> 6, bl = i & 63;
        int np1 = npT * 16 + pos_l;
        int b = b0 + bl;
        int s0 = P.S1[2 * np1], s1 = P.S1[2 * np1 + 1];
        const float* xb = P.x + (size_t)b * 6144 + 2 * np1;
        float2 c0 = *(const float2*)(xb);
        float2 c1 = *(const float2*)(xb + 2048);
        float2 c2 = *(const float2*)(xb + 4096);
        unsigned short o[8];
#pragma unroll
        for (int f = 0; f < 8; ++f) {
            int r0 = f * 3 + s0, r1 = f * 3 + s1;
            float z0 = fmaf(wl1[r0*3+2], c2.x, fmaf(wl1[r0*3+1], c1.x, fmaf(wl1[r0*3+0], c0.x, bl1[r0])));
            float z1 = fmaf(wl1[r1*3+2], c2.y, fmaf(wl1[r1*3+1], c1.y, fmaf(wl1[r1*3+0], c0.y, bl1[r1])));
            o[f] = f2bf(fmaxf(fmaxf(z0, z1), 0.f));
        }
        unsigned short* dst = &bufL1[((size_t)pos_l * 64 + bl) * 8];
        *(ushort4*)dst       = make_ushort4(o[0], o[1], o[2], o[3]);
        *(ushort4*)(dst + 4) = make_ushort4(o[4], o[5], o[6], o[7]);
    }
    __syncthreads();

    for (int i = tid; i < 512; i += 256) {
        int np_l = i >> 6, bl = i & 63;
        int np2 = npT * 8 + np_l;
        int s0 = P.S2[2 * np2], s1 = P.S2[2 * np2 + 1];
        const unsigned short* r0 = &bufL1[((size_t)(2 * np_l) * 64 + bl) * 8];
        const unsigned short* r1 = &bufL1[((size_t)(2 * np_l + 1) * 64 + bl) * 8];
        float xa[8], xb2[8];
        {
            ushort4 u0 = *(const ushort4*)r0, u1 = *(const ushort4*)(r0 + 4);
            ushort4 v0 = *(const ushort4*)r1, v1 = *(const ushort4*)(r1 + 4);
            xa[0]=bf2f(u0.x); xa[1]=bf2f(u0.y); xa[2]=bf2f(u0.z); xa[3]=bf2f(u0.w);
            xa[4]=bf2f(u1.x); xa[5]=bf2f(u1.y); xa[6]=bf2f(u1.z); xa[7]=bf2f(u1.w);
            xb2[0]=bf2f(v0.x); xb2[1]=bf2f(v0.y); xb2[2]=bf2f(v0.z); xb2[3]=bf2f(v0.w);
            xb2[4]=bf2f(v1.x); xb2[5]=bf2f(v1.y); xb2[6]=bf2f(v1.z); xb2[7]=bf2f(v1.w);
        }
        unsigned short o[32];
#pragma unroll
        for (int f = 0; f < 32; ++f) {
            const float* w0 = &wl2[(f * 3 + s0) * 8];
            const float* w1 = &wl2[(f * 3 + s1) * 8];
            float z0 = bl2[f * 3 + s0], z1 = bl2[f * 3 + s1];
#pragma unroll
            for (int k = 0; k < 8; ++k) {
                z0 = fmaf(w0[k], xa[k], z0);
                z1 = fmaf(w1[k], xb2[k], z1);
            }
            o[f] = f2bf(fmaxf(fmaxf(z0, z1), 0.f));
        }
        unsigned short* dst = P.bufA + ((size_t)np2 * 128 + b0 + bl) * 32;
#pragma unroll
        for (int i2 = 0; i2 < 8; ++i2)
            *(ushort4*)(dst + 4 * i2) = make_ushort4(o[4*i2], o[4*i2+1], o[4*i2+2], o[4*i2+3]);
    }
}

// ============================================================================
// Phase 1: L3+L4+L5 fused. 256 blocks (n5 x 4 b-quarters).
// X3 = bufA [512][128][32] -> X6 = bufB [64][128][64]
// ============================================================================
__device__ __forceinline__ void phase1(const MegaParams& P)
{
    constexpr int RPE = 72;
    __shared__ unsigned short L3o[4 * 32 * RPE];
    __shared__ unsigned short L4o[2 * 32 * RPE];

    const int tid  = threadIdx.x;
    const int lane = tid & 63;
    const int wv   = tid >> 6;
    const int c = lane & 15, q = lane >> 4;
    const int n5 = blockIdx.x >> 2;
    const int b0 = (blockIdx.x & 3) * 32;

    const unsigned short* X3  = P.bufA;
    unsigned short*       X6  = P.bufB;
    const unsigned short* W3b = P.Wb + O_W3;
    const unsigned short* W4b = P.Wb + O_W4;
    const unsigned short* W5b = P.Wb + O_W5;
    const float* B3 = P.Bl[0]; const int* S3 = P.Sl[0];
    const float* B4 = P.Bl[1]; const int* S4 = P.Sl[1];
    const float* B5 = P.Bl[2]; const int* S5 = P.Sl[2];

    for (int t = wv; t < 32; t += 4) {
        int bt = t & 1, ft = (t >> 1) & 3, j = t >> 3;
        int np = 4 * n5 + j;
        int s0 = __builtin_amdgcn_readfirstlane(S3[2 * np]);
        int s1 = __builtin_amdgcn_readfirstlane(S3[2 * np + 1]);
        int f0 = ft * 16, bl = bt * 16;
        const unsigned short* a0 = W3b + (size_t)((f0 + c) * 3 + s0) * 32 + q * 8;
        const unsigned short* a1 = W3b + (size_t)((f0 + c) * 3 + s1) * 32 + q * 8;
        const unsigned short* bp0 = X3 + ((size_t)(8 * n5 + 2 * j) * 128 + b0 + bl + c) * 32 + q * 8;
        const unsigned short* bp1 = X3 + ((size_t)(8 * n5 + 2 * j + 1) * 128 + b0 + bl + c) * 32 + q * 8;
        f32x4 acc0 = {0.f,0.f,0.f,0.f}, acc1 = {0.f,0.f,0.f,0.f};
        mfma_tile<32>(a0, a1, bp0, bp1, acc0, acc1);
        epilogue_store(&L3o[((size_t)j * 32 + bl + c) * RPE + f0 + q * 4],
                       acc0, acc1, B3, f0 + q * 4, s0, s1);
    }
    __syncthreads();

    for (int t = wv; t < 16; t += 4) {
        int bt = t & 1, ft = (t >> 1) & 3, j = t >> 3;
        int np = 2 * n5 + j;
        int s0 = __builtin_amdgcn_readfirstlane(S4[2 * np]);
        int s1 = __builtin_amdgcn_readfirstlane(S4[2 * np + 1]);
        int f0 = ft * 16, bl = bt * 16;
        const unsigned short* a0 = W4b + (size_t)((f0 + c) * 3 + s0) * 64 + q * 8;
        const unsigned short* a1 = W4b + (size_t)((f0 + c) * 3 + s1) * 64 + q * 8;
        const unsigned short* bp0 = &L3o[((size_t)(2 * j) * 32 + bl + c) * RPE + q * 8];
        const unsigned short* bp1 = &L3o[((size_t)(2 * j + 1) * 32 + bl + c) * RPE + q * 8];
        f32x4 acc0 = {0.f,0.f,0.f,0.f}, acc1 = {0.f,0.f,0.f,0.f};
        mfma_tile<64>(a0, a1, bp0, bp1, acc0, acc1);
        epilogue_store(&L4o[((size_t)j * 32 + bl + c) * RPE + f0 + q * 4],
                       acc0, acc1, B4, f0 + q * 4, s0, s1);
    }
    __syncthreads();

    for (int t = wv; t < 8; t += 4) {
        int bt = t & 1, ft = t >> 1;
        int s0 = __builtin_amdgcn_readfirstlane(S5[2 * n5]);
        int s1 = __builtin_amdgcn_readfirstlane(S5[2 * n5 + 1]);
        int f0 = ft * 16, bl = bt * 16;
        const unsigned short* a0 = W5b + (size_t)((f0 + c) * 3 + s0) * 64 + q * 8;
        const unsigned short* a1 = W5b + (size_t)((f0 + c) * 3 + s1) * 64 + q * 8;
        const unsigned short* bp0 = &L4o[((size_t)(0) * 32 + bl + c) * RPE + q * 8];
        const unsigned short* bp1 = &L4o[((size_t)(1) * 32 + bl + c) * RPE + q * 8];
        f32x4 acc0 = {0.f,0.f,0.f,0.f}, acc1 = {0.f,0.f,0.f,0.f};
        mfma_tile<64>(a0, a1, bp0, bp1, acc0, acc1);
        epilogue_store(X6 + ((size_t)n5 * 128 + b0 + bl + c) * 64 + f0 + q * 4,
                       acc0, acc1, B5, f0 + q * 4, s0, s1);
    }
}

// ============================================================================
// Phase 2: L6+L7 fused. 256 blocks = n7(16) x btile(8) x f-half(2), 4 waves.
// L6 (134 MFLOP) duplicated across the two f-halves -- cheap, avoids grid sync.
// X6 = bufB [64][128][64] -> X8 = bufA [16][128][256]
// ============================================================================
__device__ __forceinline__ void phase2(const MegaParams& P)
{
    constexpr int RPE = 136;                       // 128 + 8 pad
    __shared__ unsigned short L6o[2 * 16 * RPE];   // 8.7 KB

    const int tid  = threadIdx.x;
    const int lane = tid & 63;
    const int wv   = tid >> 6;                     // 0..3
    const int c = lane & 15, q = lane >> 4;
    const int n7   = blockIdx.x >> 4;              // 0..15
    const int sub  = blockIdx.x & 15;
    const int b0   = (sub & 7) * 16;
    const int half = sub >> 3;                     // f-half of L7

    const unsigned short* X6  = P.bufB;
    unsigned short*       X8  = P.bufA;
    const unsigned short* W6b = P.Wb + O_W6;
    const unsigned short* W7b = P.Wb + O_W7;
    const float* B6 = P.Bl[3]; const int* S6 = P.Sl[3];
    const float* B7 = P.Bl[4]; const int* S7 = P.Sl[4];

    // ---- L6 (CIN=64, CF=128): out pos 2n7+j (j=0,1), 8 f-tiles each ----
    for (int t = wv; t < 16; t += 4) {
        int j = t >> 3, ft = t & 7;
        int np = 2 * n7 + j;
        int s0 = __builtin_amdgcn_readfirstlane(S6[2 * np]);
        int s1 = __builtin_amdgcn_readfirstlane(S6[2 * np + 1]);
        int f0 = ft * 16;
        const unsigned short* a0 = W6b + (size_t)((f0 + c) * 3 + s0) * 64 + q * 8;
        const unsigned short* a1 = W6b + (size_t)((f0 + c) * 3 + s1) * 64 + q * 8;
        const unsigned short* bp0 = X6 + ((size_t)(2 * np) * 128 + b0 + c) * 64 + q * 8;
        const unsigned short* bp1 = X6 + ((size_t)(2 * np + 1) * 128 + b0 + c) * 64 + q * 8;
        f32x4 acc0 = {0.f,0.f,0.f,0.f}, acc1 = {0.f,0.f,0.f,0.f};
        mfma_tile<64>(a0, a1, bp0, bp1, acc0, acc1);
        epilogue_store(&L6o[((size_t)j * 16 + c) * RPE + f0 + q * 4],
                       acc0, acc1, B6, f0 + q * 4, s0, s1);
    }
    __syncthreads();

    // ---- L7 (CIN=128, CF=256): out pos n7, this block's 8 f-tiles ----
    {
        int s0 = __builtin_amdgcn_readfirstlane(S7[2 * n7]);
        int s1 = __builtin_amdgcn_readfirstlane(S7[2 * n7 + 1]);
        for (int t = wv; t < 8; t += 4) {
            int f0 = (half * 8 + t) * 16;
            const unsigned short* a0 = W7b + (size_t)((f0 + c) * 3 + s0) * 128 + q * 8;
            const unsigned short* a1 = W7b + (size_t)((f0 + c) * 3 + s1) * 128 + q * 8;
            const unsigned short* bp0 = &L6o[((size_t)(0) * 16 + c) * RPE + q * 8];
            const unsigned short* bp1 = &L6o[((size_t)(1) * 16 + c) * RPE + q * 8];
            f32x4 acc0 = {0.f,0.f,0.f,0.f}, acc1 = {0.f,0.f,0.f,0.f};
            mfma_tile<128>(a0, a1, bp0, bp1, acc0, acc1);
            epilogue_store(X8 + ((size_t)n7 * 128 + b0 + c) * 256 + f0 + q * 4,
                           acc0, acc1, B7, f0 + q * 4, s0, s1);
        }
    }
}

// ============================================================================
// Flat MFMA layer (L8..L11): verified R9 body, gwave-task form.
// ============================================================================
template<int CIN, int CF, int NP, int MW, int NW>
__device__ __forceinline__ void mfma_layer(
    int gwave, int lane,
    const unsigned short* __restrict__ Xin,
    const unsigned short* __restrict__ Wb,
    const float* __restrict__ bias,
    const int*   __restrict__ sel,
    unsigned short* __restrict__ Xout)
{
    constexpr int FT = CF / (16 * MW);
    constexpr int BT = 128 / (16 * NW);
    constexpr int NT = NP * FT * BT;
    if (gwave >= NT) return;

    const int task = gwave;
    const int bi = task % BT;
    const int fi = (task / BT) % FT;
    const int n  = task / (BT * FT);

    const int c = lane & 15;
    const int q = lane >> 4;
    const int s0 = __builtin_amdgcn_readfirstlane(sel[2 * n]);
    const int s1 = __builtin_amdgcn_readfirstlane(sel[2 * n + 1]);

    const int f0 = fi * 16 * MW;
    const int b0 = bi * 16 * NW;

    const unsigned short* ap[2][MW];
    const unsigned short* bp[2][NW];
#pragma unroll
    for (int p = 0; p < 2; ++p) {
        int s = p ? s1 : s0;
#pragma unroll
        for (int mi = 0; mi < MW; ++mi)
            ap[p][mi] = Wb + (size_t)((f0 + mi * 16 + c) * 3 + s) * CIN + q * 8;
#pragma unroll
        for (int ni = 0; ni < NW; ++ni)
            bp[p][ni] = Xin + ((size_t)(2 * n + p) * 128 + b0 + ni * 16 + c) * CIN + q * 8;
    }

    f32x4 acc[2][MW][NW];
#pragma unroll
    for (int p = 0; p < 2; ++p)
#pragma unroll
        for (int mi = 0; mi < MW; ++mi)
#pragma unroll
            for (int ni = 0; ni < NW; ++ni)
                acc[p][mi][ni] = (f32x4){0.f, 0.f, 0.f, 0.f};

#pragma unroll 2
    for (int k = 0; k < CIN; k += 32) {
        bf16x8 A[2][MW], B[2][NW];
#pragma unroll
        for (int p = 0; p < 2; ++p) {
#pragma unroll
            for (int mi = 0; mi < MW; ++mi)
                A[p][mi] = __builtin_bit_cast(bf16x8, *(const float4*)(const void*)(ap[p][mi] + k));
#pragma unroll
            for (int ni = 0; ni < NW; ++ni)
                B[p][ni] = __builtin_bit_cast(bf16x8, *(const float4*)(const void*)(bp[p][ni] + k));
        }
#pragma unroll
        for (int p = 0; p < 2; ++p)
#pragma unroll
            for (int mi = 0; mi < MW; ++mi)
#pragma unroll
                for (int ni = 0; ni < NW; ++ni)
                    acc[p][mi][ni] = __builtin_amdgcn_mfma_f32_16x16x32_bf16(
                        A[p][mi], B[p][ni], acc[p][mi][ni], 0, 0, 0);
    }

#pragma unroll
    for (int mi = 0; mi < MW; ++mi) {
        int fbase = f0 + mi * 16 + q * 4;
#pragma unroll
        for (int ni = 0; ni < NW; ++ni) {
            int b = b0 + ni * 16 + c;
            epilogue_store(Xout + ((size_t)n * 128 + b) * CF + fbase,
                           acc[0][mi][ni], acc[1][mi][ni], bias, fbase, s0, s1);
        }
    }
}

// ============================================================================
// FC head: h bf16 = bufA [128][1024]; out [128][16] fp32 log-softmax
// ============================================================================
__device__ __forceinline__ void phase_fc(const MegaParams& P)
{
    if (blockIdx.x >= 128) return;
    __shared__ float red[16][17];
    __shared__ float logits[16];

    int b   = blockIdx.x;
    int tid = threadIdx.x;
    int k     = tid & 15;
    int chunk = tid >> 4;

    const float* __restrict__ wk = P.fcW + (size_t)k * 1024;
    const unsigned short* hb = P.bufA + (size_t)b * 1024;

    float partial = 0.0f;
    int j0 = chunk * 64;
#pragma unroll 8
    for (int j = 0; j < 64; ++j)
        partial = fmaf(bf2f(hb[j0 + j]), wk[j0 + j], partial);

    red[chunk][k] = partial;
    __syncthreads();

    if (tid < 16) {
        float s = P.fcb[tid];
#pragma unroll
        for (int c = 0; c < 16; ++c) s += red[c][tid];
        logits[tid] = s;
    }
    __syncthreads();

    if (tid < 16) {
        float mx = -INFINITY;
#pragma unroll
        for (int kk = 0; kk < 16; ++kk) mx = fmaxf(mx, logits[kk]);
        float se = 0.0f;
#pragma unroll
        for (int kk = 0; kk < 16; ++kk) se += expf(logits[kk] - mx);
        P.out[b * 16 + tid] = logits[tid] - mx - logf(se);
    }
}

// ============================================================================
// The whole network in ONE cooperative kernel: 256 blocks x 256 threads,
// 7 grid syncs. __threadfence() = agent-scope wbL2+inv around each sync
// handles cross-XCD L2 non-coherence of the produced intermediates.
// ============================================================================
__global__ __launch_bounds__(256) void meganet(MegaParams P)
{
    cg::grid_group grid = cg::this_grid();
    const int gwave = blockIdx.x * 4 + (threadIdx.x >> 6);
    const int lane  = threadIdx.x & 63;

    phase0(P);                                            // pack || L1+L2 -> bufA
    __threadfence(); grid.sync(); __threadfence();
    phase1(P);                                            // L3-5 -> bufB
    __threadfence(); grid.sync(); __threadfence();
    phase2(P);                                            // L6-7 -> bufA
    __threadfence(); grid.sync(); __threadfence();
    mfma_layer<256, 512, 8, 2, 1>(gwave, lane, P.bufA, P.Wb + O_W8,  P.Bl[5], P.Sl[5], P.bufB);
    __threadfence(); grid.sync(); __threadfence();
    mfma_layer<512, 512, 4, 1, 1>(gwave, lane, P.bufB, P.Wb + O_W9,  P.Bl[6], P.Sl[6], P.bufA);
    __threadfence(); grid.sync(); __threadfence();
    mfma_layer<512, 512, 2, 1, 1>(gwave, lane, P.bufA, P.Wb + O_W10, P.Bl[7], P.Sl[7], P.bufB);
    __threadfence(); grid.sync(); __threadfence();
    mfma_layer<512, 1024, 1, 1, 1>(gwave, lane, P.bufB, P.Wb + O_W11, P.Bl[8], P.Sl[8], P.bufA);
    __threadfence(); grid.sync(); __threadfence();
    phase_fc(P);                                          // bufA -> out
}

// ============================================================================
// Fallback wrappers (identical bodies as 8 dispatches) in case cooperative
// launch is rejected under graph capture.
// ============================================================================
__global__ __launch_bounds__(256) void k_phase0(MegaParams P) { phase0(P); }
__global__ __launch_bounds__(256) void k_phase1(MegaParams P) { phase1(P); }
__global__ __launch_bounds__(256) void k_phase2(MegaParams P) { phase2(P); }
__global__ __launch_bounds__(256) void k_fc(MegaParams P)     { phase_fc(P); }

template<int CIN, int CF, int NP, int MW, int NW>
__global__ __launch_bounds__(256) void k_mfma(
    const unsigned short* __restrict__ Xin,
    const unsigned short* __restrict__ Wb,
    const float* __restrict__ bias,
    const int*   __restrict__ sel,
    unsigned short* __restrict__ Xout)
{
    mfma_layer<CIN, CF, NP, MW, NW>(blockIdx.x * 4 + (threadIdx.x >> 6),
                                    threadIdx.x & 63, Xin, Wb, bias, sel, Xout);
}

// ============================================================================
extern "C" void kernel_launch(void* const* d_in, const int* in_sizes, int n_in,
                              void* d_out, int out_size, void* d_ws, size_t ws_size,
                              hipStream_t stream)
{
    MegaParams P;
    P.x  = (const float*)d_in[0];
    P.W1 = (const float*)d_in[1]; P.B1 = (const float*)d_in[2]; P.S1 = (const int*)d_in[3];
    P.W2 = (const float*)d_in[4]; P.B2 = (const float*)d_in[5]; P.S2 = (const int*)d_in[6];
    for (int i = 0; i < 9; ++i) {
        P.Wsrc[i] = (const float*)d_in[7 + 3 * i];
        P.Bl[i]   = (const float*)d_in[8 + 3 * i];
        P.Sl[i]   = (const int*)  d_in[9 + 3 * i];
    }
    P.fcW = (const float*)d_in[34];
    P.fcb = (const float*)d_in[35];

    unsigned short* bufA = (unsigned short*)d_ws;
    P.bufA = bufA;                                    // 4 MB
    P.bufB = bufA + 2u * 1024u * 1024u;               // 4 MB
    P.Wb   = P.bufB + 2u * 1024u * 1024u;             // packed W3..W11 bf16
    P.out  = (float*)d_out;

    void* args[] = { (void*)&P };
    hipError_t err = hipLaunchCooperativeKernel(meganet, dim3(256), dim3(256),
                                                (void**)args, 0u, stream);
    if (err != hipSuccess) {
        // Fallback: same phase bodies as 8 plain dispatches.
        k_phase0<<<256, 256, 0, stream>>>(P);
        k_phase1<<<256, 256, 0, stream>>>(P);
        k_phase2<<<256, 256, 0, stream>>>(P);
        k_mfma<256, 512, 8, 2, 1><<<256, 256, 0, stream>>>(P.bufA, P.Wb + O_W8,  P.Bl[5], P.Sl[5], P.bufB);
        k_mfma<512, 512, 4, 1, 1><<<256, 256, 0, stream>>>(P.bufB, P.Wb + O_W9,  P.Bl[6], P.Sl[6], P.bufA);
        k_mfma<512, 512, 2, 1, 1><<<128, 256, 0, stream>>>(P.bufA, P.Wb + O_W10, P.Bl[7], P.Sl[7], P.bufB);
        k_mfma<512, 1024, 1, 1, 1><<<128, 256, 0, stream>>>(P.bufB, P.Wb + O_W11, P.Bl[8], P.Sl[8], P.bufA);
        k_fc<<<128, 256, 0, stream>>>(P);
    }
}

// Round 2
// 208.716 us; speedup vs baseline: 3.6086x; 3.6086x over previous
//
#include <hip/hip_runtime.h>
#include <math.h>

typedef __attribute__((ext_vector_type(8))) short bf16x8;
typedef __attribute__((ext_vector_type(4))) float f32x4;

__device__ __forceinline__ unsigned short f2bf(float f) {
    unsigned u = __builtin_bit_cast(unsigned, f);
    u += 0x7FFF + ((u >> 16) & 1);          // RNE
    return (unsigned short)(u >> 16);
}
__device__ __forceinline__ float bf2f(unsigned short h) {
    unsigned u = ((unsigned)h) << 16;
    return __builtin_bit_cast(float, u);
}

// Packed-weight offsets inside Wb (bf16 elements) -- only W8..W11 used now
#define O_W8 153600
#define O_W9 546816
#define O_W10 1333248
#define O_W11 2119680

// ============================================================================
// MFMA helpers (verified R9/R11/R12 of previous session)
// ============================================================================
template<int CIN>
__device__ __forceinline__ void mfma_tile(
    const unsigned short* a0, const unsigned short* a1,
    const unsigned short* b0p, const unsigned short* b1p,
    f32x4& acc0, f32x4& acc1)
{
#pragma unroll
    for (int k = 0; k < CIN; k += 32) {
        bf16x8 A0 = __builtin_bit_cast(bf16x8, *(const float4*)(const void*)(a0 + k));
        bf16x8 A1 = __builtin_bit_cast(bf16x8, *(const float4*)(const void*)(a1 + k));
        bf16x8 B0 = __builtin_bit_cast(bf16x8, *(const float4*)(const void*)(b0p + k));
        bf16x8 B1 = __builtin_bit_cast(bf16x8, *(const float4*)(const void*)(b1p + k));
        acc0 = __builtin_amdgcn_mfma_f32_16x16x32_bf16(A0, B0, acc0, 0, 0, 0);
        acc1 = __builtin_amdgcn_mfma_f32_16x16x32_bf16(A1, B1, acc1, 0, 0, 0);
    }
}

__device__ __forceinline__ void epilogue_store(
    unsigned short* dst, const f32x4& acc0, const f32x4& acc1,
    const float* bias, int fbase, int s0, int s1)
{
    unsigned short o[4];
#pragma unroll
    for (int r = 0; r < 4; ++r) {
        float v = fmaxf(fmaxf(acc0[r] + bias[(fbase + r) * 3 + s0],
                              acc1[r] + bias[(fbase + r) * 3 + s1]), 0.f);
        o[r] = f2bf(v);
    }
    *(ushort4*)dst = make_ushort4(o[0], o[1], o[2], o[3]);
}

__device__ __forceinline__ bf16x8 cvt8(const float* p) {
    float4 u0 = *(const float4*)p;
    float4 u1 = *(const float4*)(p + 4);
    bf16x8 r;
    r[0] = (short)f2bf(u0.x); r[1] = (short)f2bf(u0.y);
    r[2] = (short)f2bf(u0.z); r[3] = (short)f2bf(u0.w);
    r[4] = (short)f2bf(u1.x); r[5] = (short)f2bf(u1.y);
    r[6] = (short)f2bf(u1.z); r[7] = (short)f2bf(u1.w);
    return r;
}

// ============================================================================
// Fused L1..L7 kernel.
//   blocks 0..127  : bg = blk>>4 (16-batch group), sl = blk&15 (128-input-pos
//                    slice). Whole L1-L7 chain in a 120 KB LDS arena.
//                    Writes X8[pos16][b128][256] bf16 to global.
//   blocks 128..191: pack W8..W11 fp32 -> bf16 into Wb (overlapped).
// Position nesting: slice owns input pos [sl*128,(sl+1)*128); layer-l local
// out count = 64>>(l-1); global out pos = sl*(64>>(l-1)) + n_local.
// All LDS row pitches are multiples of 8 elems (16 B align for ds_read_b128)
// and chosen so the 16 c-lanes land on >=8 distinct banks (<=2-way, free).
// ============================================================================
struct FusedParams {
    const float* x;
    const float* W1; const float* B1; const int* S1;
    const float* W2; const float* B2; const int* S2;
    const float* Wsrc[9];          // W3..W11 fp32
    const float* Bl[9];            // B3..B11
    const int*   Sl[9];            // S3..S11
    unsigned short* Wb;            // packed bf16 (W8..W11 regions used)
    unsigned short* X8;            // out: [16][128][256] bf16
};

// Arena offsets (bytes, 16B aligned). Lifetimes verified phase by phase:
#define A_XS   0        // float  [16][3][132]  in: L1            (25344 B)
#define A_L1O  25344    // ushort [64][16][8]   L1->L2            (16384 B)
#define A_WSM  41728    // float  W1[72] B1[24] W2[768] B2[96]    ( 3840 B)
#define A_L2O  45568    // ushort [32][16][40]  L2->L3            (40960 B)
#define A_WB3  0        // ushort [192][40]     (xs dead)         (15360 B)
#define A_L3O  86528    // ushort [16][16][72]  L3->L4            (36864 B)
#define A_WB4  45568    // ushort [192][72]     (L2O dead)        (27648 B)
#define A_L4O  0        // ushort [8][16][72]   (WB3 dead)        (18432 B)
#define A_WB5  18432    // ushort [192][72]     (L1O/WSM dead)    (27648 B)
#define A_L5O  46080    // ushort [4][16][72]   (WB4 dead)        ( 9216 B)
#define A_WB6  55296    // ushort [384][72]     (L3O dead)        (55296 B)
#define A_L6O  0        // ushort [2][16][136]  (L4O dead)        ( 8704 B)
#define ARENA_BYTES 123392

__global__ __launch_bounds__(512) void fused17_kernel(FusedParams P)
{
    const int tid = threadIdx.x;

    if (blockIdx.x >= 128) {
        // ---- pack W8..W11 ----
        int gt = (blockIdx.x - 128) * 512 + tid;
        const int we[4] = {393216, 786432, 786432, 1572864};
        const int wo[4] = {O_W8, O_W9, O_W10, O_W11};
#pragma unroll
        for (int li = 0; li < 4; ++li) {
            const float4* src = (const float4*)P.Wsrc[5 + li];
            ushort4* dst = (ushort4*)(P.Wb + wo[li]);
            int n4 = we[li] >> 2;
            for (int i = gt; i < n4; i += 32768) {
                float4 w = src[i];
                dst[i] = make_ushort4(f2bf(w.x), f2bf(w.y), f2bf(w.z), f2bf(w.w));
            }
        }
        return;
    }

    __shared__ __align__(16) char arena[ARENA_BYTES];

    const int bg   = blockIdx.x >> 4;      // 0..7  (batch b = bg*16 + 0..15)
    const int sl   = blockIdx.x & 15;      // 0..15 (input pos slice)
    const int lane = tid & 63;
    const int wv   = tid >> 6;             // 0..7
    const int c    = lane & 15, q = lane >> 4;

    // ---- stage x slice + L1/L2 weights ----
    {
        float* xsf = (float*)(arena + A_XS);
        const float* xg = P.x + (size_t)(bg * 16) * 6144 + sl * 128;
        for (int i = tid; i < 6144; i += 512) {
            int b = i / 384;
            int r = i - b * 384;
            int cc = r >> 7, p = r & 127;
            xsf[b * 396 + cc * 132 + p] = xg[(size_t)b * 6144 + cc * 2048 + p];
        }
        float* wsm = (float*)(arena + A_WSM);
        for (int i = tid; i < 960; i += 512) {
            float v;
            if (i < 72)       v = P.W1[i];
            else if (i < 96)  v = P.B1[i - 72];
            else if (i < 864) v = P.W2[i - 96];
            else              v = P.B2[i - 864];
            wsm[i] = v;
        }
    }
    __syncthreads();

    // ---- L1 (cf=8, cin=3, VALU): 64 out pos x 16 b ----
    {
        const float* xsf = (const float*)(arena + A_XS);
        const float* wl1 = (const float*)(arena + A_WSM);
        const float* bl1 = wl1 + 72;
        unsigned short* L1o = (unsigned short*)(arena + A_L1O);
        for (int i = tid; i < 1024; i += 512) {
            int n = i >> 4, b = i & 15;
            int np1 = sl * 64 + n;
            int s0 = P.S1[2 * np1], s1 = P.S1[2 * np1 + 1];
            const float* xb0 = xsf + b * 396 + 2 * n;
            float c0x = xb0[0],   c0y = xb0[1];
            float c1x = xb0[132], c1y = xb0[133];
            float c2x = xb0[264], c2y = xb0[265];
            unsigned short o[8];
#pragma unroll
            for (int f = 0; f < 8; ++f) {
                int r0 = f * 3 + s0, r1 = f * 3 + s1;
                float z0 = fmaf(wl1[r0*3+2], c2x, fmaf(wl1[r0*3+1], c1x, fmaf(wl1[r0*3+0], c0x, bl1[r0])));
                float z1 = fmaf(wl1[r1*3+2], c2y, fmaf(wl1[r1*3+1], c1y, fmaf(wl1[r1*3+0], c0y, bl1[r1])));
                o[f] = f2bf(fmaxf(fmaxf(z0, z1), 0.f));
            }
            unsigned short* dst = L1o + (n * 16 + b) * 8;
            *(ushort4*)dst       = make_ushort4(o[0], o[1], o[2], o[3]);
            *(ushort4*)(dst + 4) = make_ushort4(o[4], o[5], o[6], o[7]);
        }
    }
    __syncthreads();

    // ---- L2 (cf=32, cin=8, VALU): 32 out pos x 16 b ----
    {
        const float* wl2 = (const float*)(arena + A_WSM) + 96;
        const float* bl2 = (const float*)(arena + A_WSM) + 864;
        const unsigned short* L1o = (const unsigned short*)(arena + A_L1O);
        unsigned short* L2o = (unsigned short*)(arena + A_L2O);
        {
            int i = tid;  // exactly 512 items
            int n = i >> 4, b = i & 15;
            int np2 = sl * 32 + n;
            int s0 = P.S2[2 * np2], s1 = P.S2[2 * np2 + 1];
            const unsigned short* r0 = L1o + ((2 * n) * 16 + b) * 8;
            const unsigned short* r1 = L1o + ((2 * n + 1) * 16 + b) * 8;
            float xa[8], xb2[8];
            {
                ushort4 u0 = *(const ushort4*)r0, u1 = *(const ushort4*)(r0 + 4);
                ushort4 v0 = *(const ushort4*)r1, v1 = *(const ushort4*)(r1 + 4);
                xa[0]=bf2f(u0.x); xa[1]=bf2f(u0.y); xa[2]=bf2f(u0.z); xa[3]=bf2f(u0.w);
                xa[4]=bf2f(u1.x); xa[5]=bf2f(u1.y); xa[6]=bf2f(u1.z); xa[7]=bf2f(u1.w);
                xb2[0]=bf2f(v0.x); xb2[1]=bf2f(v0.y); xb2[2]=bf2f(v0.z); xb2[3]=bf2f(v0.w);
                xb2[4]=bf2f(v1.x); xb2[5]=bf2f(v1.y); xb2[6]=bf2f(v1.z); xb2[7]=bf2f(v1.w);
            }
            unsigned short o[32];
#pragma unroll
            for (int f = 0; f < 32; ++f) {
                const float* w0 = &wl2[(f * 3 + s0) * 8];
                const float* w1 = &wl2[(f * 3 + s1) * 8];
                float z0 = bl2[f * 3 + s0], z1 = bl2[f * 3 + s1];
#pragma unroll
                for (int k = 0; k < 8; ++k) {
                    z0 = fmaf(w0[k], xa[k], z0);
                    z1 = fmaf(w1[k], xb2[k], z1);
                }
                o[f] = f2bf(fmaxf(fmaxf(z0, z1), 0.f));
            }
            unsigned short* dst = L2o + (n * 16 + b) * 40;
#pragma unroll
            for (int i2 = 0; i2 < 8; ++i2)
                *(ushort4*)(dst + 4 * i2) = make_ushort4(o[4*i2], o[4*i2+1], o[4*i2+2], o[4*i2+3]);
        }
    }
    __syncthreads();

    // ---- stage W3 bf16 -> LDS [192][40] ----
    {
        unsigned short* wb = (unsigned short*)(arena + A_WB3);
        const float* Wf = P.Wsrc[0];
        for (int i = tid; i < 6144; i += 512) {
            int row = i >> 5, k = i & 31;
            wb[row * 40 + k] = f2bf(Wf[i]);
        }
    }
    __syncthreads();

    // ---- L3 (cf=64, cin=32, MFMA): 16 out pos x 4 ftiles = 64 tasks ----
    {
        const unsigned short* wb  = (const unsigned short*)(arena + A_WB3);
        const unsigned short* L2o = (const unsigned short*)(arena + A_L2O);
        unsigned short* L3o = (unsigned short*)(arena + A_L3O);
        const int* S3 = P.Sl[0]; const float* B3 = P.Bl[0];
        for (int t = wv; t < 64; t += 8) {
            int n3 = t >> 2, ft = t & 3;
            int np = sl * 16 + n3;
            int s0 = __builtin_amdgcn_readfirstlane(S3[2 * np]);
            int s1 = __builtin_amdgcn_readfirstlane(S3[2 * np + 1]);
            int f0 = ft * 16;
            const unsigned short* a0 = wb + ((f0 + c) * 3 + s0) * 40 + q * 8;
            const unsigned short* a1 = wb + ((f0 + c) * 3 + s1) * 40 + q * 8;
            const unsigned short* bp0 = L2o + ((2 * n3) * 16 + c) * 40 + q * 8;
            const unsigned short* bp1 = L2o + ((2 * n3 + 1) * 16 + c) * 40 + q * 8;
            f32x4 acc0 = {0.f,0.f,0.f,0.f}, acc1 = {0.f,0.f,0.f,0.f};
            mfma_tile<32>(a0, a1, bp0, bp1, acc0, acc1);
            epilogue_store(L3o + (n3 * 16 + c) * 72 + f0 + q * 4,
                           acc0, acc1, B3, f0 + q * 4, s0, s1);
        }
    }
    __syncthreads();

    // ---- stage W4 bf16 -> LDS [192][72] ----
    {
        unsigned short* wb = (unsigned short*)(arena + A_WB4);
        const float* Wf = P.Wsrc[1];
        for (int i = tid; i < 12288; i += 512) {
            int row = i >> 6, k = i & 63;
            wb[row * 72 + k] = f2bf(Wf[i]);
        }
    }
    __syncthreads();

    // ---- L4 (cf=64, cin=64): 8 out pos x 4 ftiles = 32 tasks ----
    {
        const unsigned short* wb  = (const unsigned short*)(arena + A_WB4);
        const unsigned short* L3o = (const unsigned short*)(arena + A_L3O);
        unsigned short* L4o = (unsigned short*)(arena + A_L4O);
        const int* S4 = P.Sl[1]; const float* B4 = P.Bl[1];
        for (int t = wv; t < 32; t += 8) {
            int n4 = t >> 2, ft = t & 3;
            int np = sl * 8 + n4;
            int s0 = __builtin_amdgcn_readfirstlane(S4[2 * np]);
            int s1 = __builtin_amdgcn_readfirstlane(S4[2 * np + 1]);
            int f0 = ft * 16;
            const unsigned short* a0 = wb + ((f0 + c) * 3 + s0) * 72 + q * 8;
            const unsigned short* a1 = wb + ((f0 + c) * 3 + s1) * 72 + q * 8;
            const unsigned short* bp0 = L3o + ((2 * n4) * 16 + c) * 72 + q * 8;
            const unsigned short* bp1 = L3o + ((2 * n4 + 1) * 16 + c) * 72 + q * 8;
            f32x4 acc0 = {0.f,0.f,0.f,0.f}, acc1 = {0.f,0.f,0.f,0.f};
            mfma_tile<64>(a0, a1, bp0, bp1, acc0, acc1);
            epilogue_store(L4o + (n4 * 16 + c) * 72 + f0 + q * 4,
                           acc0, acc1, B4, f0 + q * 4, s0, s1);
        }
    }
    __syncthreads();

    // ---- stage W5 bf16 -> LDS [192][72] ----
    {
        unsigned short* wb = (unsigned short*)(arena + A_WB5);
        const float* Wf = P.Wsrc[2];
        for (int i = tid; i < 12288; i += 512) {
            int row = i >> 6, k = i & 63;
            wb[row * 72 + k] = f2bf(Wf[i]);
        }
    }
    __syncthreads();

    // ---- L5 (cf=64, cin=64): 4 out pos x 4 ftiles = 16 tasks ----
    {
        const unsigned short* wb  = (const unsigned short*)(arena + A_WB5);
        const unsigned short* L4o = (const unsigned short*)(arena + A_L4O);
        unsigned short* L5o = (unsigned short*)(arena + A_L5O);
        const int* S5 = P.Sl[2]; const float* B5 = P.Bl[2];
        for (int t = wv; t < 16; t += 8) {
            int n5 = t >> 2, ft = t & 3;
            int np = sl * 4 + n5;
            int s0 = __builtin_amdgcn_readfirstlane(S5[2 * np]);
            int s1 = __builtin_amdgcn_readfirstlane(S5[2 * np + 1]);
            int f0 = ft * 16;
            const unsigned short* a0 = wb + ((f0 + c) * 3 + s0) * 72 + q * 8;
            const unsigned short* a1 = wb + ((f0 + c) * 3 + s1) * 72 + q * 8;
            const unsigned short* bp0 = L4o + ((2 * n5) * 16 + c) * 72 + q * 8;
            const unsigned short* bp1 = L4o + ((2 * n5 + 1) * 16 + c) * 72 + q * 8;
            f32x4 acc0 = {0.f,0.f,0.f,0.f}, acc1 = {0.f,0.f,0.f,0.f};
            mfma_tile<64>(a0, a1, bp0, bp1, acc0, acc1);
            epilogue_store(L5o + (n5 * 16 + c) * 72 + f0 + q * 4,
                           acc0, acc1, B5, f0 + q * 4, s0, s1);
        }
    }
    __syncthreads();

    // ---- stage W6 bf16 -> LDS [384][72] ----
    {
        unsigned short* wb = (unsigned short*)(arena + A_WB6);
        const float* Wf = P.Wsrc[3];
        for (int i = tid; i < 24576; i += 512) {
            int row = i >> 6, k = i & 63;
            wb[row * 72 + k] = f2bf(Wf[i]);
        }
    }
    __syncthreads();

    // ---- L6 (cf=128, cin=64): 2 out pos x 8 ftiles = 16 tasks ----
    {
        const unsigned short* wb  = (const unsigned short*)(arena + A_WB6);
        const unsigned short* L5o = (const unsigned short*)(arena + A_L5O);
        unsigned short* L6o = (unsigned short*)(arena + A_L6O);
        const int* S6 = P.Sl[3]; const float* B6 = P.Bl[3];
        for (int t = wv; t < 16; t += 8) {
            int n6 = t >> 3, ft = t & 7;
            int np = sl * 2 + n6;
            int s0 = __builtin_amdgcn_readfirstlane(S6[2 * np]);
            int s1 = __builtin_amdgcn_readfirstlane(S6[2 * np + 1]);
            int f0 = ft * 16;
            const unsigned short* a0 = wb + ((f0 + c) * 3 + s0) * 72 + q * 8;
            const unsigned short* a1 = wb + ((f0 + c) * 3 + s1) * 72 + q * 8;
            const unsigned short* bp0 = L5o + ((2 * n6) * 16 + c) * 72 + q * 8;
            const unsigned short* bp1 = L5o + ((2 * n6 + 1) * 16 + c) * 72 + q * 8;
            f32x4 acc0 = {0.f,0.f,0.f,0.f}, acc1 = {0.f,0.f,0.f,0.f};
            mfma_tile<64>(a0, a1, bp0, bp1, acc0, acc1);
            epilogue_store(L6o + (n6 * 16 + c) * 136 + f0 + q * 4,
                           acc0, acc1, B6, f0 + q * 4, s0, s1);
        }
    }
    __syncthreads();

    // ---- L7 (cf=256, cin=128): 1 out pos x 16 ftiles; A from global fp32 ----
    {
        const unsigned short* L6o = (const unsigned short*)(arena + A_L6O);
        const float* W7f = P.Wsrc[4];
        const int* S7 = P.Sl[4]; const float* B7 = P.Bl[4];
        int s0 = __builtin_amdgcn_readfirstlane(S7[2 * sl]);
        int s1 = __builtin_amdgcn_readfirstlane(S7[2 * sl + 1]);
        for (int t = wv; t < 16; t += 8) {
            int f0 = t * 16;
            const float* wa0 = W7f + (size_t)((f0 + c) * 3 + s0) * 128;
            const float* wa1 = W7f + (size_t)((f0 + c) * 3 + s1) * 128;
            const unsigned short* bp0 = L6o + (0 * 16 + c) * 136;
            const unsigned short* bp1 = L6o + (1 * 16 + c) * 136;
            f32x4 acc0 = {0.f,0.f,0.f,0.f}, acc1 = {0.f,0.f,0.f,0.f};
#pragma unroll
            for (int k = 0; k < 128; k += 32) {
                bf16x8 A0 = cvt8(wa0 + k + q * 8);
                bf16x8 A1 = cvt8(wa1 + k + q * 8);
                bf16x8 B0 = __builtin_bit_cast(bf16x8, *(const float4*)(const void*)(bp0 + k + q * 8));
                bf16x8 B1 = __builtin_bit_cast(bf16x8, *(const float4*)(const void*)(bp1 + k + q * 8));
                acc0 = __builtin_amdgcn_mfma_f32_16x16x32_bf16(A0, B0, acc0, 0, 0, 0);
                acc1 = __builtin_amdgcn_mfma_f32_16x16x32_bf16(A1, B1, acc1, 0, 0, 0);
            }
            epilogue_store(P.X8 + ((size_t)sl * 128 + bg * 16 + c) * 256 + f0 + q * 4,
                           acc0, acc1, B7, f0 + q * 4, s0, s1);
        }
    }
}

// ============================================================================
// Flat MFMA layer (L8..L11): verified R9 body (R0 verbatim).
// ============================================================================
template<int CIN, int CF, int NP, int MW, int NW>
__global__ __launch_bounds__(256) void mfma_kernel(
    const unsigned short* __restrict__ Xin,
    const unsigned short* __restrict__ Wb,
    const float* __restrict__ bias,
    const int*   __restrict__ sel,
    unsigned short* __restrict__ Xout)
{
    constexpr int FT = CF / (16 * MW);
    constexpr int BT = 128 / (16 * NW);

    const int wid  = threadIdx.x >> 6;
    const int lane = threadIdx.x & 63;
    const int task = blockIdx.x * 4 + wid;
    const int bi = task % BT;
    const int fi = (task / BT) % FT;
    const int n  = task / (BT * FT);

    const int c = lane & 15;
    const int q = lane >> 4;
    const int s0 = __builtin_amdgcn_readfirstlane(sel[2 * n]);
    const int s1 = __builtin_amdgcn_readfirstlane(sel[2 * n + 1]);

    const int f0 = fi * 16 * MW;
    const int b0 = bi * 16 * NW;

    const unsigned short* ap[2][MW];
    const unsigned short* bp[2][NW];
#pragma unroll
    for (int p = 0; p < 2; ++p) {
        int s = p ? s1 : s0;
#pragma unroll
        for (int mi = 0; mi < MW; ++mi)
            ap[p][mi] = Wb + (size_t)((f0 + mi * 16 + c) * 3 + s) * CIN + q * 8;
#pragma unroll
        for (int ni = 0; ni < NW; ++ni)
            bp[p][ni] = Xin + ((size_t)(2 * n + p) * 128 + b0 + ni * 16 + c) * CIN + q * 8;
    }

    f32x4 acc[2][MW][NW];
#pragma unroll
    for (int p = 0; p < 2; ++p)
#pragma unroll
        for (int mi = 0; mi < MW; ++mi)
#pragma unroll
            for (int ni = 0; ni < NW; ++ni)
                acc[p][mi][ni] = (f32x4){0.f, 0.f, 0.f, 0.f};

#pragma unroll 2
    for (int k = 0; k < CIN; k += 32) {
        bf16x8 A[2][MW], B[2][NW];
#pragma unroll
        for (int p = 0; p < 2; ++p) {
#pragma unroll
            for (int mi = 0; mi < MW; ++mi)
                A[p][mi] = __builtin_bit_cast(bf16x8, *(const float4*)(const void*)(ap[p][mi] + k));
#pragma unroll
            for (int ni = 0; ni < NW; ++ni)
                B[p][ni] = __builtin_bit_cast(bf16x8, *(const float4*)(const void*)(bp[p][ni] + k));
        }
#pragma unroll
        for (int p = 0; p < 2; ++p)
#pragma unroll
            for (int mi = 0; mi < MW; ++mi)
#pragma unroll
                for (int ni = 0; ni < NW; ++ni)
                    acc[p][mi][ni] = __builtin_amdgcn_mfma_f32_16x16x32_bf16(
                        A[p][mi], B[p][ni], acc[p][mi][ni], 0, 0, 0);
    }

#pragma unroll
    for (int mi = 0; mi < MW; ++mi) {
        int fbase = f0 + mi * 16 + q * 4;
#pragma unroll
        for (int ni = 0; ni < NW; ++ni) {
            int b = b0 + ni * 16 + c;
            epilogue_store(Xout + ((size_t)n * 128 + b) * CF + fbase,
                           acc[0][mi][ni], acc[1][mi][ni], bias, fbase, s0, s1);
        }
    }
}

// ============================================================================
// FC head: h bf16 [128][1024]; out [128][16] fp32 log-softmax (R0 verbatim)
// ============================================================================
__global__ __launch_bounds__(256) void fc_logsoftmax_kernel(
    const unsigned short* __restrict__ h, const float* __restrict__ fcW,
    const float* __restrict__ fcb, float* __restrict__ out)
{
    int b   = blockIdx.x;
    int tid = threadIdx.x;
    int k     = tid & 15;
    int chunk = tid >> 4;

    const float* __restrict__ wk = fcW + (size_t)k * 1024;
    const unsigned short* hb = h + (size_t)b * 1024;

    float partial = 0.0f;
    int j0 = chunk * 64;
#pragma unroll 8
    for (int j = 0; j < 64; ++j)
        partial = fmaf(bf2f(hb[j0 + j]), wk[j0 + j], partial);

    __shared__ float red[16][17];
    red[chunk][k] = partial;
    __syncthreads();

    __shared__ float logits[16];
    if (tid < 16) {
        float s = fcb[tid];
#pragma unroll
        for (int c = 0; c < 16; ++c) s += red[c][tid];
        logits[tid] = s;
    }
    __syncthreads();

    if (tid < 16) {
        float mx = -INFINITY;
#pragma unroll
        for (int kk = 0; kk < 16; ++kk) mx = fmaxf(mx, logits[kk]);
        float se = 0.0f;
#pragma unroll
        for (int kk = 0; kk < 16; ++kk) se += expf(logits[kk] - mx);
        out[b * 16 + tid] = logits[tid] - mx - logf(se);
    }
}

// ============================================================================
extern "C" void kernel_launch(void* const* d_in, const int* in_sizes, int n_in,
                              void* d_out, int out_size, void* d_ws, size_t ws_size,
                              hipStream_t stream)
{
#define WL(i) (const float*)d_in[1 + 3 * (i)]
#define BL(i) (const float*)d_in[2 + 3 * (i)]
#define SL(i) (const int*)  d_in[3 + 3 * (i)]

    unsigned short* bufA = (unsigned short*)d_ws;          // 4 MB
    unsigned short* bufB = bufA + 2u * 1024u * 1024u;      // 4 MB
    unsigned short* Wb   = bufB + 2u * 1024u * 1024u;      // packed bf16 W8..W11

    // ---- K1: fused L1..L7 -> X8 (bufA)  ||  pack W8..W11 -> Wb ----
    FusedParams FP;
    FP.x  = (const float*)d_in[0];
    FP.W1 = WL(0); FP.B1 = BL(0); FP.S1 = SL(0);
    FP.W2 = WL(1); FP.B2 = BL(1); FP.S2 = SL(1);
    for (int i = 0; i < 9; ++i) {
        FP.Wsrc[i] = WL(2 + i);
        FP.Bl[i]   = BL(2 + i);
        FP.Sl[i]   = SL(2 + i);
    }
    FP.Wb = Wb; FP.X8 = bufA;
    fused17_kernel<<<192, 512, 0, stream>>>(FP);

    // ---- K2..K5: flat MFMA layers L8..L11 (R0-verified configs) ----
    mfma_kernel<256, 512, 8, 2, 2><<<128, 256, 0, stream>>>(bufA, Wb + O_W8,  BL(7),  SL(7),  bufB);
    mfma_kernel<512, 512, 4, 1, 1><<<256, 256, 0, stream>>>(bufB, Wb + O_W9,  BL(8),  SL(8),  bufA);
    mfma_kernel<512, 512, 2, 1, 1><<<128, 256, 0, stream>>>(bufA, Wb + O_W10, BL(9),  SL(9),  bufB);
    mfma_kernel<512, 1024, 1, 1, 1><<<128, 256, 0, stream>>>(bufB, Wb + O_W11, BL(10), SL(10), bufA);

    // ---- K6: FC ----
    fc_logsoftmax_kernel<<<128, 256, 0, stream>>>(bufA, (const float*)d_in[34], (const float*)d_in[35], (float*)d_out);

#undef WL
#undef BL
#undef SL
}